// Round 1
// baseline (613.234 us; speedup 1.0000x reference)
//
#include <hip/hip_runtime.h>
#include <hip/hip_bf16.h>

#define F_IN 128
#define H_DIM 64

// ---------------- GEMM1: h0 = x @ W1  [N,128]@[128,64] ----------------
// 16 rows per block of 256 threads; thread (t>>4 = row-in-block, (t&15)*4 = col group).
__global__ __launch_bounds__(256) void gemm1_k(const float* __restrict__ x,
                                               const float* __restrict__ W1,
                                               float* __restrict__ h, int N) {
    __shared__ float w1s[F_IN * H_DIM];  // 32 KB
    int t = threadIdx.x;
    for (int i = t; i < F_IN * H_DIM; i += 256) w1s[i] = W1[i];
    __syncthreads();
    int r = blockIdx.x * 16 + (t >> 4);
    if (r >= N) return;
    int cg = (t & 15) * 4;
    const float* xr = x + (size_t)r * F_IN;
    float a0 = 0.f, a1 = 0.f, a2 = 0.f, a3 = 0.f;
#pragma unroll 4
    for (int k = 0; k < F_IN; ++k) {
        float xv = xr[k];
        float4 w = *reinterpret_cast<const float4*>(&w1s[k * H_DIM + cg]);
        a0 = fmaf(xv, w.x, a0);
        a1 = fmaf(xv, w.y, a1);
        a2 = fmaf(xv, w.z, a2);
        a3 = fmaf(xv, w.w, a3);
    }
    float4 o = {a0, a1, a2, a3};
    *reinterpret_cast<float4*>(&h[(size_t)r * H_DIM + cg]) = o;
}

// ---------------- GEMM2: z2 = relu(agg1) @ W2  [N,64]@[64,64] ----------------
__global__ __launch_bounds__(256) void gemm2_k(const float* __restrict__ agg,
                                               const float* __restrict__ W2,
                                               float* __restrict__ z2, int N) {
    __shared__ float w2s[H_DIM * H_DIM];  // 16 KB
    int t = threadIdx.x;
    for (int i = t; i < H_DIM * H_DIM; i += 256) w2s[i] = W2[i];
    __syncthreads();
    int r = blockIdx.x * 16 + (t >> 4);
    if (r >= N) return;
    int cg = (t & 15) * 4;
    const float* ar = agg + (size_t)r * H_DIM;
    float a0 = 0.f, a1 = 0.f, a2 = 0.f, a3 = 0.f;
#pragma unroll 4
    for (int k = 0; k < H_DIM; ++k) {
        float xv = fmaxf(ar[k], 0.f);  // fused relu on the aggregated input
        float4 w = *reinterpret_cast<const float4*>(&w2s[k * H_DIM + cg]);
        a0 = fmaf(xv, w.x, a0);
        a1 = fmaf(xv, w.y, a1);
        a2 = fmaf(xv, w.z, a2);
        a3 = fmaf(xv, w.w, a3);
    }
    float4 o = {a0, a1, a2, a3};
    *reinterpret_cast<float4*>(&z2[(size_t)r * H_DIM + cg]) = o;
}

// ---------------- scatter: out[dst[e]] += w[e] * h[src[e]]  (wave per edge) ----------------
__global__ __launch_bounds__(256) void scatter_k(const float* __restrict__ h,
                                                 const int* __restrict__ ei,  // [2,E] flat
                                                 const float* __restrict__ w,
                                                 float* __restrict__ out, int E) {
    int e = blockIdx.x * 4 + (threadIdx.x >> 6);
    if (e >= E) return;
    int lane = threadIdx.x & 63;
    int s = ei[e];
    int d = ei[E + e];
    float wt = w[e];
    float v = wt * h[(size_t)s * H_DIM + lane];
    atomicAdd(&out[(size_t)d * H_DIM + lane], v);
}

// ---------------- decode: out[p,:] = [z[s], z[t]] @ Wlin.T  (wave per pair) ----------------
__global__ __launch_bounds__(256) void decode_k(const float* __restrict__ z,
                                                const int* __restrict__ pos,  // [2,P] flat
                                                const float* __restrict__ Wlin,  // [2,128]
                                                float* __restrict__ out, int P) {
    int p = blockIdx.x * 4 + (threadIdx.x >> 6);
    if (p >= P) return;
    int lane = threadIdx.x & 63;
    int s = pos[p];
    int t = pos[P + p];
    float zs = z[(size_t)s * H_DIM + lane];
    float zt = z[(size_t)t * H_DIM + lane];
    float a0 = fmaf(zs, Wlin[lane], zt * Wlin[64 + lane]);
    float a1 = fmaf(zs, Wlin[128 + lane], zt * Wlin[192 + lane]);
#pragma unroll
    for (int off = 32; off > 0; off >>= 1) {
        a0 += __shfl_down(a0, off);
        a1 += __shfl_down(a1, off);
    }
    if (lane == 0) {
        out[(size_t)p * 2] = a0;
        out[(size_t)p * 2 + 1] = a1;
    }
}

extern "C" void kernel_launch(void* const* d_in, const int* in_sizes, int n_in,
                              void* d_out, int out_size, void* d_ws, size_t ws_size,
                              hipStream_t stream) {
    const float* x    = (const float*)d_in[0];
    const int*   ei   = (const int*)d_in[1];    // [2,E]
    const float* ew   = (const float*)d_in[2];  // [E]
    const int*   pos  = (const int*)d_in[3];    // [2,P]
    const float* W1   = (const float*)d_in[4];  // [128,64]
    const float* W2   = (const float*)d_in[5];  // [64,64]
    const float* Wlin = (const float*)d_in[6];  // [2,128]
    float* out = (float*)d_out;

    const int N = in_sizes[0] / F_IN;      // 100000
    const int E = in_sizes[2];             // 1000000
    const int P = in_sizes[3] / 2;         // 500000

    float* bufA = (float*)d_ws;                    // N*64 f32
    float* bufB = bufA + (size_t)N * H_DIM;        // N*64 f32
    const size_t nodeBytes = (size_t)N * H_DIM * sizeof(float);

    // conv1: h0 = x @ W1 -> bufA
    gemm1_k<<<(N + 15) / 16, 256, 0, stream>>>(x, W1, bufA, N);
    // agg1 -> bufB (zeroed)
    hipMemsetAsync(bufB, 0, nodeBytes, stream);
    scatter_k<<<(E + 3) / 4, 256, 0, stream>>>(bufA, ei, ew, bufB, E);
    // conv2 matmul: z2 = relu(agg1) @ W2 -> bufA
    gemm2_k<<<(N + 15) / 16, 256, 0, stream>>>(bufB, W2, bufA, N);
    // agg2 (z) -> bufB (zeroed)
    hipMemsetAsync(bufB, 0, nodeBytes, stream);
    scatter_k<<<(E + 3) / 4, 256, 0, stream>>>(bufA, ei, ew, bufB, E);
    // decode
    decode_k<<<(P + 3) / 4, 256, 0, stream>>>(bufB, pos, Wlin, out, P);
}

// Round 2
// 405.717 us; speedup vs baseline: 1.5115x; 1.5115x over previous
//
#include <hip/hip_runtime.h>
#include <hip/hip_bf16.h>

#define F_IN 128
#define H_DIM 64

// ---------------- GEMM1: h0 = x @ W1  [N,128]@[128,64] ----------------
__global__ __launch_bounds__(256) void gemm1_k(const float* __restrict__ x,
                                               const float* __restrict__ W1,
                                               float* __restrict__ h, int N) {
    __shared__ float w1s[F_IN * H_DIM];  // 32 KB
    int t = threadIdx.x;
    for (int i = t; i < F_IN * H_DIM; i += 256) w1s[i] = W1[i];
    __syncthreads();
    int r = blockIdx.x * 16 + (t >> 4);
    if (r >= N) return;
    int cg = (t & 15) * 4;
    const float* xr = x + (size_t)r * F_IN;
    float a0 = 0.f, a1 = 0.f, a2 = 0.f, a3 = 0.f;
#pragma unroll 4
    for (int k = 0; k < F_IN; ++k) {
        float xv = xr[k];
        float4 w = *reinterpret_cast<const float4*>(&w1s[k * H_DIM + cg]);
        a0 = fmaf(xv, w.x, a0);
        a1 = fmaf(xv, w.y, a1);
        a2 = fmaf(xv, w.z, a2);
        a3 = fmaf(xv, w.w, a3);
    }
    float4 o = {a0, a1, a2, a3};
    *reinterpret_cast<float4*>(&h[(size_t)r * H_DIM + cg]) = o;
}

// ---------------- GEMM2: z2 = relu(agg1) @ W2  [N,64]@[64,64] ----------------
__global__ __launch_bounds__(256) void gemm2_k(const float* __restrict__ agg,
                                               const float* __restrict__ W2,
                                               float* __restrict__ z2, int N) {
    __shared__ float w2s[H_DIM * H_DIM];  // 16 KB
    int t = threadIdx.x;
    for (int i = t; i < H_DIM * H_DIM; i += 256) w2s[i] = W2[i];
    __syncthreads();
    int r = blockIdx.x * 16 + (t >> 4);
    if (r >= N) return;
    int cg = (t & 15) * 4;
    const float* ar = agg + (size_t)r * H_DIM;
    float a0 = 0.f, a1 = 0.f, a2 = 0.f, a3 = 0.f;
#pragma unroll 4
    for (int k = 0; k < H_DIM; ++k) {
        float xv = fmaxf(ar[k], 0.f);  // fused relu on the aggregated input
        float4 w = *reinterpret_cast<const float4*>(&w2s[k * H_DIM + cg]);
        a0 = fmaf(xv, w.x, a0);
        a1 = fmaf(xv, w.y, a1);
        a2 = fmaf(xv, w.z, a2);
        a3 = fmaf(xv, w.w, a3);
    }
    float4 o = {a0, a1, a2, a3};
    *reinterpret_cast<float4*>(&z2[(size_t)r * H_DIM + cg]) = o;
}

// ---------------- CSR build ----------------
__global__ __launch_bounds__(256) void count_k(const int* __restrict__ ei, int* __restrict__ deg, int E) {
    int e = blockIdx.x * 256 + threadIdx.x;
    if (e < E) atomicAdd(&deg[ei[E + e]], 1);
}

// per-block reduce of deg -> blocksum[b]
__global__ __launch_bounds__(256) void scan1_k(const int* __restrict__ deg, int* __restrict__ blocksum, int N) {
    __shared__ int ls[4];
    int i = blockIdx.x * 256 + threadIdx.x;
    int v = (i < N) ? deg[i] : 0;
#pragma unroll
    for (int off = 32; off > 0; off >>= 1) v += __shfl_down(v, off);
    int wid = threadIdx.x >> 6;
    if ((threadIdx.x & 63) == 0) ls[wid] = v;
    __syncthreads();
    if (threadIdx.x == 0) blocksum[blockIdx.x] = ls[0] + ls[1] + ls[2] + ls[3];
}

// exclusive scan of blocksum (NB <= 512) -> blockoff
__global__ __launch_bounds__(512) void scan2_k(const int* __restrict__ blocksum, int* __restrict__ blockoff, int NB) {
    __shared__ int s[512];
    int t = threadIdx.x;
    int v = (t < NB) ? blocksum[t] : 0;
    s[t] = v;
    __syncthreads();
    for (int off = 1; off < 512; off <<= 1) {
        int add = (t >= off) ? s[t - off] : 0;
        __syncthreads();
        s[t] += add;
        __syncthreads();
    }
    if (t < NB) blockoff[t] = s[t] - v;  // exclusive
}

// per-block exclusive scan + blockoff -> rowptr (row starts)
__global__ __launch_bounds__(256) void scan3_k(const int* __restrict__ deg, const int* __restrict__ blockoff,
                                               int* __restrict__ rowptr, int N) {
    __shared__ int s[256];
    int t = threadIdx.x;
    int i = blockIdx.x * 256 + t;
    int v = (i < N) ? deg[i] : 0;
    s[t] = v;
    __syncthreads();
    for (int off = 1; off < 256; off <<= 1) {
        int add = (t >= off) ? s[t - off] : 0;
        __syncthreads();
        s[t] += add;
        __syncthreads();
    }
    if (i < N) rowptr[i] = s[t] - v + blockoff[blockIdx.x];
}

// fill: slot = rowptr[dst] + cursor[dst]++ ; epack[slot] = (src, w)
__global__ __launch_bounds__(256) void fill_k(const int* __restrict__ ei, const float* __restrict__ w,
                                              const int* __restrict__ rowptr, int* __restrict__ cursor,
                                              int2* __restrict__ epack, int E) {
    int e = blockIdx.x * 256 + threadIdx.x;
    if (e >= E) return;
    int d = ei[E + e];
    int slot = rowptr[d] + atomicAdd(&cursor[d], 1);
    epack[slot] = make_int2(ei[e], __float_as_int(w[e]));
}

// ---------------- aggregation: out[n,:] = sum_j w_j * h[src_j,:]  (wave per node) ----------------
__global__ __launch_bounds__(256) void agg_k(const float* __restrict__ h,
                                             const int* __restrict__ rowptr, const int* __restrict__ deg,
                                             const int2* __restrict__ epack,
                                             float* __restrict__ out, int N) {
    int node = blockIdx.x * 4 + (threadIdx.x >> 6);
    if (node >= N) return;
    int lane = threadIdx.x & 63;
    int start = rowptr[node];
    int cnt = deg[node];
    float acc0 = 0.f, acc1 = 0.f;
    int j = 0;
    for (; j + 1 < cnt; j += 2) {
        int2 p0 = epack[start + j];
        int2 p1 = epack[start + j + 1];
        acc0 = fmaf(__int_as_float(p0.y), h[(size_t)p0.x * H_DIM + lane], acc0);
        acc1 = fmaf(__int_as_float(p1.y), h[(size_t)p1.x * H_DIM + lane], acc1);
    }
    if (j < cnt) {
        int2 p0 = epack[start + j];
        acc0 = fmaf(__int_as_float(p0.y), h[(size_t)p0.x * H_DIM + lane], acc0);
    }
    out[(size_t)node * H_DIM + lane] = acc0 + acc1;
}

// ---------------- decode: out[p,:] = [z[s], z[t]] @ Wlin.T  (wave per pair) ----------------
__global__ __launch_bounds__(256) void decode_k(const float* __restrict__ z,
                                                const int* __restrict__ pos,  // [2,P] flat
                                                const float* __restrict__ Wlin,  // [2,128]
                                                float* __restrict__ out, int P) {
    int p = blockIdx.x * 4 + (threadIdx.x >> 6);
    if (p >= P) return;
    int lane = threadIdx.x & 63;
    int s = pos[p];
    int t = pos[P + p];
    float zs = z[(size_t)s * H_DIM + lane];
    float zt = z[(size_t)t * H_DIM + lane];
    float a0 = fmaf(zs, Wlin[lane], zt * Wlin[64 + lane]);
    float a1 = fmaf(zs, Wlin[128 + lane], zt * Wlin[192 + lane]);
#pragma unroll
    for (int off = 32; off > 0; off >>= 1) {
        a0 += __shfl_down(a0, off);
        a1 += __shfl_down(a1, off);
    }
    if (lane == 0) {
        out[(size_t)p * 2] = a0;
        out[(size_t)p * 2 + 1] = a1;
    }
}

extern "C" void kernel_launch(void* const* d_in, const int* in_sizes, int n_in,
                              void* d_out, int out_size, void* d_ws, size_t ws_size,
                              hipStream_t stream) {
    const float* x    = (const float*)d_in[0];
    const int*   ei   = (const int*)d_in[1];    // [2,E]
    const float* ew   = (const float*)d_in[2];  // [E]
    const int*   pos  = (const int*)d_in[3];    // [2,P]
    const float* W1   = (const float*)d_in[4];  // [128,64]
    const float* W2   = (const float*)d_in[5];  // [64,64]
    const float* Wlin = (const float*)d_in[6];  // [2,128]
    float* out = (float*)d_out;

    const int N = in_sizes[0] / F_IN;      // 100000
    const int E = in_sizes[2];             // 1000000
    const int P = in_sizes[3] / 2;         // 500000
    const int NB = (N + 255) / 256;        // 391

    // workspace layout (element offsets, all 8B-aligned)
    float* bufA    = (float*)d_ws;                         // N*64 f32
    float* bufB    = bufA + (size_t)N * H_DIM;             // N*64 f32
    int*   deg     = (int*)(bufB + (size_t)N * H_DIM);     // N
    int*   rowptr  = deg + N;                              // N
    int*   cursor  = rowptr + N;                           // N
    int*   blocksum= cursor + N;                           // NB
    int*   blockoff= blocksum + NB;                        // NB
    // round up to 8B alignment for int2
    size_t ep_off = ((size_t)(blockoff + NB - (int*)d_ws) + 1) & ~(size_t)1;
    int2*  epack   = (int2*)((int*)d_ws + ep_off);         // E int2

    // conv1 matmul
    gemm1_k<<<(N + 15) / 16, 256, 0, stream>>>(x, W1, bufA, N);

    // CSR build (once; reused by both aggregations)
    hipMemsetAsync(deg, 0, (size_t)N * sizeof(int), stream);
    hipMemsetAsync(cursor, 0, (size_t)N * sizeof(int), stream);
    count_k<<<(E + 255) / 256, 256, 0, stream>>>(ei, deg, E);
    scan1_k<<<NB, 256, 0, stream>>>(deg, blocksum, N);
    scan2_k<<<1, 512, 0, stream>>>(blocksum, blockoff, NB);
    scan3_k<<<NB, 256, 0, stream>>>(deg, blockoff, rowptr, N);
    fill_k<<<(E + 255) / 256, 256, 0, stream>>>(ei, ew, rowptr, cursor, epack, E);

    // agg1: bufA -> bufB
    agg_k<<<(N + 3) / 4, 256, 0, stream>>>(bufA, rowptr, deg, epack, bufB, N);
    // conv2 matmul (relu fused on input): bufB -> bufA
    gemm2_k<<<(N + 15) / 16, 256, 0, stream>>>(bufB, W2, bufA, N);
    // agg2: bufA -> bufB
    agg_k<<<(N + 3) / 4, 256, 0, stream>>>(bufA, rowptr, deg, epack, bufB, N);
    // decode
    decode_k<<<(P + 3) / 4, 256, 0, stream>>>(bufB, pos, Wlin, out, P);
}

// Round 3
// 311.571 us; speedup vs baseline: 1.9682x; 1.3022x over previous
//
#include <hip/hip_runtime.h>
#include <hip/hip_bf16.h>

#define F_IN 128
#define H_DIM 64

// ---------------- GEMM1: h0 = x @ W1  [N,128]@[128,64] ----------------
__global__ __launch_bounds__(256) void gemm1_k(const float* __restrict__ x,
                                               const float* __restrict__ W1,
                                               float* __restrict__ h, int N) {
    __shared__ float w1s[F_IN * H_DIM];  // 32 KB
    int t = threadIdx.x;
    for (int i = t; i < F_IN * H_DIM; i += 256) w1s[i] = W1[i];
    __syncthreads();
    int r = blockIdx.x * 16 + (t >> 4);
    if (r >= N) return;
    int cg = (t & 15) * 4;
    const float* xr = x + (size_t)r * F_IN;
    float a0 = 0.f, a1 = 0.f, a2 = 0.f, a3 = 0.f;
#pragma unroll 4
    for (int k = 0; k < F_IN; ++k) {
        float xv = xr[k];
        float4 w = *reinterpret_cast<const float4*>(&w1s[k * H_DIM + cg]);
        a0 = fmaf(xv, w.x, a0);
        a1 = fmaf(xv, w.y, a1);
        a2 = fmaf(xv, w.z, a2);
        a3 = fmaf(xv, w.w, a3);
    }
    float4 o = {a0, a1, a2, a3};
    *reinterpret_cast<float4*>(&h[(size_t)r * H_DIM + cg]) = o;
}

// ---------------- GEMM2: z2 = relu(agg1) @ W2  [N,64]@[64,64] ----------------
__global__ __launch_bounds__(256) void gemm2_k(const float* __restrict__ agg,
                                               const float* __restrict__ W2,
                                               float* __restrict__ z2, int N) {
    __shared__ float w2s[H_DIM * H_DIM];  // 16 KB
    int t = threadIdx.x;
    for (int i = t; i < H_DIM * H_DIM; i += 256) w2s[i] = W2[i];
    __syncthreads();
    int r = blockIdx.x * 16 + (t >> 4);
    if (r >= N) return;
    int cg = (t & 15) * 4;
    const float* ar = agg + (size_t)r * H_DIM;
    float a0 = 0.f, a1 = 0.f, a2 = 0.f, a3 = 0.f;
#pragma unroll 4
    for (int k = 0; k < H_DIM; ++k) {
        float xv = fmaxf(ar[k], 0.f);  // fused relu on the aggregated input
        float4 w = *reinterpret_cast<const float4*>(&w2s[k * H_DIM + cg]);
        a0 = fmaf(xv, w.x, a0);
        a1 = fmaf(xv, w.y, a1);
        a2 = fmaf(xv, w.z, a2);
        a3 = fmaf(xv, w.w, a3);
    }
    float4 o = {a0, a1, a2, a3};
    *reinterpret_cast<float4*>(&z2[(size_t)r * H_DIM + cg]) = o;
}

// ---------------- CSR build ----------------
__global__ __launch_bounds__(256) void count_k(const int* __restrict__ ei, int* __restrict__ deg, int E) {
    int e = blockIdx.x * 256 + threadIdx.x;
    if (e < E) atomicAdd(&deg[ei[E + e]], 1);
}

__global__ __launch_bounds__(256) void scan1_k(const int* __restrict__ deg, int* __restrict__ blocksum, int N) {
    __shared__ int ls[4];
    int i = blockIdx.x * 256 + threadIdx.x;
    int v = (i < N) ? deg[i] : 0;
#pragma unroll
    for (int off = 32; off > 0; off >>= 1) v += __shfl_down(v, off);
    int wid = threadIdx.x >> 6;
    if ((threadIdx.x & 63) == 0) ls[wid] = v;
    __syncthreads();
    if (threadIdx.x == 0) blocksum[blockIdx.x] = ls[0] + ls[1] + ls[2] + ls[3];
}

__global__ __launch_bounds__(512) void scan2_k(const int* __restrict__ blocksum, int* __restrict__ blockoff, int NB) {
    __shared__ int s[512];
    int t = threadIdx.x;
    int v = (t < NB) ? blocksum[t] : 0;
    s[t] = v;
    __syncthreads();
    for (int off = 1; off < 512; off <<= 1) {
        int add = (t >= off) ? s[t - off] : 0;
        __syncthreads();
        s[t] += add;
        __syncthreads();
    }
    if (t < NB) blockoff[t] = s[t] - v;  // exclusive
}

__global__ __launch_bounds__(256) void scan3_k(const int* __restrict__ deg, const int* __restrict__ blockoff,
                                               int* __restrict__ rowptr, int N) {
    __shared__ int s[256];
    int t = threadIdx.x;
    int i = blockIdx.x * 256 + t;
    int v = (i < N) ? deg[i] : 0;
    s[t] = v;
    __syncthreads();
    for (int off = 1; off < 256; off <<= 1) {
        int add = (t >= off) ? s[t - off] : 0;
        __syncthreads();
        s[t] += add;
        __syncthreads();
    }
    if (i < N) rowptr[i] = s[t] - v + blockoff[blockIdx.x];
}

__global__ __launch_bounds__(256) void fill_k(const int* __restrict__ ei, const float* __restrict__ w,
                                              const int* __restrict__ rowptr, int* __restrict__ cursor,
                                              int2* __restrict__ epack, int E) {
    int e = blockIdx.x * 256 + threadIdx.x;
    if (e >= E) return;
    int d = ei[E + e];
    int slot = rowptr[d] + atomicAdd(&cursor[d], 1);
    epack[slot] = make_int2(ei[e], __float_as_int(w[e]));
}

// ---------------- aggregation: out[n,:] = sum_j w_j * h[src_j,:]  (wave per node) ----------------
__global__ __launch_bounds__(256) void agg_k(const float* __restrict__ h,
                                             const int* __restrict__ rowptr, const int* __restrict__ deg,
                                             const int2* __restrict__ epack,
                                             float* __restrict__ out, int N) {
    int node = blockIdx.x * 4 + (threadIdx.x >> 6);
    if (node >= N) return;
    int lane = threadIdx.x & 63;
    int start = rowptr[node];
    int cnt = deg[node];
    float acc0 = 0.f, acc1 = 0.f, acc2 = 0.f, acc3 = 0.f;
    int j = 0;
    for (; j + 3 < cnt; j += 4) {
        int2 p0 = epack[start + j];
        int2 p1 = epack[start + j + 1];
        int2 p2 = epack[start + j + 2];
        int2 p3 = epack[start + j + 3];
        acc0 = fmaf(__int_as_float(p0.y), h[(size_t)p0.x * H_DIM + lane], acc0);
        acc1 = fmaf(__int_as_float(p1.y), h[(size_t)p1.x * H_DIM + lane], acc1);
        acc2 = fmaf(__int_as_float(p2.y), h[(size_t)p2.x * H_DIM + lane], acc2);
        acc3 = fmaf(__int_as_float(p3.y), h[(size_t)p3.x * H_DIM + lane], acc3);
    }
    for (; j < cnt; ++j) {
        int2 p0 = epack[start + j];
        acc0 = fmaf(__int_as_float(p0.y), h[(size_t)p0.x * H_DIM + lane], acc0);
    }
    out[(size_t)node * H_DIM + lane] = (acc0 + acc1) + (acc2 + acc3);
}

// ---------------- projection: u[n] = (z·A0, z·A1, z·B0, z·B1) ----------------
// 16 lanes per node (lane g handles 4 dims), 4 nodes per wave, 16 nodes/block.
__global__ __launch_bounds__(256) void proj_k(const float* __restrict__ z,
                                              const float* __restrict__ Wlin,  // [2,128]
                                              float4* __restrict__ u, int N) {
    int node = blockIdx.x * 16 + (threadIdx.x >> 4);
    if (node >= N) return;
    int g = threadIdx.x & 15;
    float4 z4 = *reinterpret_cast<const float4*>(&z[(size_t)node * H_DIM + g * 4]);
    float4 a0 = *reinterpret_cast<const float4*>(&Wlin[g * 4]);          // row0, src half
    float4 b0 = *reinterpret_cast<const float4*>(&Wlin[64 + g * 4]);     // row0, dst half
    float4 a1 = *reinterpret_cast<const float4*>(&Wlin[128 + g * 4]);    // row1, src half
    float4 b1 = *reinterpret_cast<const float4*>(&Wlin[192 + g * 4]);    // row1, dst half
    float p0 = z4.x * a0.x + z4.y * a0.y + z4.z * a0.z + z4.w * a0.w;
    float p1 = z4.x * a1.x + z4.y * a1.y + z4.z * a1.z + z4.w * a1.w;
    float p2 = z4.x * b0.x + z4.y * b0.y + z4.z * b0.z + z4.w * b0.w;
    float p3 = z4.x * b1.x + z4.y * b1.y + z4.z * b1.z + z4.w * b1.w;
#pragma unroll
    for (int m = 8; m > 0; m >>= 1) {
        p0 += __shfl_xor(p0, m);
        p1 += __shfl_xor(p1, m);
        p2 += __shfl_xor(p2, m);
        p3 += __shfl_xor(p3, m);
    }
    if (g == 0) u[node] = make_float4(p0, p1, p2, p3);
}

// ---------------- pair decode: out[p] = (u[s].x+u[t].z, u[s].y+u[t].w) ----------------
__global__ __launch_bounds__(256) void pair_k(const float4* __restrict__ u,
                                              const int* __restrict__ pos,  // [2,P] flat
                                              float2* __restrict__ out, int P) {
    int p = blockIdx.x * 256 + threadIdx.x;
    if (p >= P) return;
    int s = pos[p];
    int t = pos[P + p];
    float4 us = u[s];
    float4 ut = u[t];
    out[p] = make_float2(us.x + ut.z, us.y + ut.w);
}

extern "C" void kernel_launch(void* const* d_in, const int* in_sizes, int n_in,
                              void* d_out, int out_size, void* d_ws, size_t ws_size,
                              hipStream_t stream) {
    const float* x    = (const float*)d_in[0];
    const int*   ei   = (const int*)d_in[1];    // [2,E]
    const float* ew   = (const float*)d_in[2];  // [E]
    const int*   pos  = (const int*)d_in[3];    // [2,P]
    const float* W1   = (const float*)d_in[4];  // [128,64]
    const float* W2   = (const float*)d_in[5];  // [64,64]
    const float* Wlin = (const float*)d_in[6];  // [2,128]
    float* out = (float*)d_out;

    const int N = in_sizes[0] / F_IN;      // 100000
    const int E = in_sizes[2];             // 1000000
    const int P = in_sizes[3] / 2;         // 500000
    const int NB = (N + 255) / 256;        // 391

    // workspace layout
    float* bufA    = (float*)d_ws;                         // N*64 f32
    float* bufB    = bufA + (size_t)N * H_DIM;             // N*64 f32
    int*   deg     = (int*)(bufB + (size_t)N * H_DIM);     // N
    int*   rowptr  = deg + N;                              // N
    int*   cursor  = rowptr + N;                           // N
    int*   blocksum= cursor + N;                           // NB
    int*   blockoff= blocksum + NB;                        // NB
    size_t ep_off = ((size_t)(blockoff + NB - (int*)d_ws) + 1) & ~(size_t)1;
    int2*  epack   = (int2*)((int*)d_ws + ep_off);         // E int2
    float4* u      = (float4*)bufA;                        // N float4 (reuses bufA after agg2)

    // conv1 matmul
    gemm1_k<<<(N + 15) / 16, 256, 0, stream>>>(x, W1, bufA, N);

    // CSR build (once; reused by both aggregations)
    hipMemsetAsync(deg, 0, (size_t)N * sizeof(int), stream);
    hipMemsetAsync(cursor, 0, (size_t)N * sizeof(int), stream);
    count_k<<<(E + 255) / 256, 256, 0, stream>>>(ei, deg, E);
    scan1_k<<<NB, 256, 0, stream>>>(deg, blocksum, N);
    scan2_k<<<1, 512, 0, stream>>>(blocksum, blockoff, NB);
    scan3_k<<<NB, 256, 0, stream>>>(deg, blockoff, rowptr, N);
    fill_k<<<(E + 255) / 256, 256, 0, stream>>>(ei, ew, rowptr, cursor, epack, E);

    // agg1: bufA -> bufB
    agg_k<<<(N + 3) / 4, 256, 0, stream>>>(bufA, rowptr, deg, epack, bufB, N);
    // conv2 matmul (relu fused on input): bufB -> bufA
    gemm2_k<<<(N + 15) / 16, 256, 0, stream>>>(bufB, W2, bufA, N);
    // agg2: bufA -> bufB   (bufA free afterwards)
    agg_k<<<(N + 3) / 4, 256, 0, stream>>>(bufA, rowptr, deg, epack, bufB, N);
    // per-node projection: z=bufB -> u (in bufA)
    proj_k<<<(N + 15) / 16, 256, 0, stream>>>(bufB, Wlin, u, N);
    // pair decode
    pair_k<<<(P + 255) / 256, 256, 0, stream>>>(u, pos, (float2*)out, P);
}